// Round 1
// baseline (3346.535 us; speedup 1.0000x reference)
//
#include <hip/hip_runtime.h>
#include <math.h>

// Problem constants
#define B_ 8
#define C_ 256
#define H_ 56
#define W_ 56
#define N_ 3136  // 56*56 = 49*64

// Workspace layout (floats). Total = 8,078,336 floats = 32.3 MB.
#define QK_OFF 0
#define VT_OFF (B_*64*N_)             // q: ch 0..31, k: ch 32..63, each [B][64][N]
#define M_OFF  (VT_OFF + B_*N_*C_)    // vT: [B][N][C]
#define L_OFF  (M_OFF + B_*N_)        // m: [B][N], rl: [B][N]

// ---------------------------------------------------------------------------
// Kernel 1: fused 3x3 SAME conv for q (32ch), k (32ch), v (256ch).
// grid (10 ocg, 7 ytile, 8 b), block 448 (= 8 rows x 56 cols, 7 waves).
// x slab staged in LDS per 8-channel chunk; weights read via wave-uniform
// (scalar) loads. q,k written [B][64][N]; v written TRANSPOSED [B][N][C].
// ---------------------------------------------------------------------------
__global__ __launch_bounds__(448) void conv_qkv_kernel(
    const float* __restrict__ x,
    const float* __restrict__ wq, const float* __restrict__ bq,
    const float* __restrict__ wk, const float* __restrict__ bk,
    const float* __restrict__ wv, const float* __restrict__ bv,
    float* __restrict__ qk, float* __restrict__ vt)
{
    __shared__ float xs[8*10*58];  // [chunk 8][rows 10][cols 58], 18.56 KB
    const int ocg = blockIdx.x;    // 0=q, 1=k, 2..9=v groups of 32
    const int yt  = blockIdx.y;
    const int b   = blockIdx.z;
    const int tid = threadIdx.x;
    const int py  = tid / 56;      // 0..7
    const int px  = tid % 56;
    const int y0  = yt * 8;

    const float* wsel;
    const float* bsel;
    int obase;
    if (ocg == 0)      { wsel = wq; bsel = bq; obase = 0; }
    else if (ocg == 1) { wsel = wk; bsel = bk; obase = 0; }
    else               { wsel = wv; bsel = bv; obase = (ocg - 2) * 32; }

    float acc[32];
#pragma unroll
    for (int o = 0; o < 32; o++) acc[o] = 0.0f;

    for (int c0 = 0; c0 < C_; c0 += 8) {
        __syncthreads();
        // stage x[b, c0..c0+7, y0-1..y0+8, -1..56] with zero padding
        for (int idx = tid; idx < 8*10*58; idx += 448) {
            const int ch  = idx / 580;
            const int rem = idx - ch * 580;
            const int r   = rem / 58;
            const int col = rem - r * 58;
            const int gy = y0 - 1 + r;
            const int gx = col - 1;
            float v = 0.0f;
            if (gy >= 0 && gy < H_ && gx >= 0 && gx < W_)
                v = x[((size_t)(b*C_ + c0 + ch)*H_ + gy)*W_ + gx];
            xs[idx] = v;
        }
        __syncthreads();

        for (int ch = 0; ch < 8; ch++) {
            const float* xb = &xs[ch*580 + py*58 + px];
            const float t0 = xb[0],   t1 = xb[1],   t2 = xb[2];
            const float t3 = xb[58],  t4 = xb[59],  t5 = xb[60];
            const float t6 = xb[116], t7 = xb[117], t8 = xb[118];
            const float* wrow = wsel + (size_t)(obase*C_ + (c0 + ch)) * 9;
#pragma unroll
            for (int o = 0; o < 32; o++) {
                const float* wo = wrow + (size_t)o * (C_*9);  // uniform -> s_load
                acc[o] += t0*wo[0] + t1*wo[1] + t2*wo[2]
                        + t3*wo[3] + t4*wo[4] + t5*wo[5]
                        + t6*wo[6] + t7*wo[7] + t8*wo[8];
            }
        }
    }

    const int i = (y0 + py) * W_ + px;
    if (ocg <= 1) {
        float* dst = qk + ((size_t)b*64 + (ocg == 1 ? 32 : 0)) * N_ + i;
#pragma unroll
        for (int o = 0; o < 32; o++)
            dst[(size_t)o * N_] = acc[o] + bsel[o];
    } else {
        float* dst = vt + ((size_t)b*N_ + i) * C_ + obase;
#pragma unroll
        for (int o = 0; o < 32; o++) acc[o] += bsel[obase + o];
#pragma unroll
        for (int o = 0; o < 32; o += 4) {
            float4 vv = make_float4(acc[o], acc[o+1], acc[o+2], acc[o+3]);
            *(float4*)(dst + o) = vv;
        }
    }
}

// ---------------------------------------------------------------------------
// Kernel 2: softmax statistics pass. Per (i-tile of 64, b): running row max m
// and row sum l over all 3136 j. S computed with 4x4 register tiles from LDS
// q/k tiles. Threads t<64 own one row each (m_run,l_run in registers).
// ---------------------------------------------------------------------------
__global__ __launch_bounds__(256) void attn_ml_kernel(
    const float* __restrict__ qk, float* __restrict__ mrow, float* __restrict__ lrow)
{
    __shared__ float q_lds[32*64];
    __shared__ float k_lds[32*64];
    __shared__ float red[16*64];
    __shared__ float mbc[64];
    const int ibt = blockIdx.x;
    const int b   = blockIdx.y;
    const int t   = threadIdx.x;
    const int ti = t & 15, tj = t >> 4;
    const int i0 = ti * 4, j0 = tj * 4;
    const float* qb = qk + (size_t)b * 64 * N_;
    {
        const int d = t >> 3, seg = (t & 7) * 8;
        const float* src = qb + (size_t)d * N_ + ibt*64 + seg;
        *(float4*)&q_lds[d*64 + seg]     = *(const float4*)(src);
        *(float4*)&q_lds[d*64 + seg + 4] = *(const float4*)(src + 4);
    }
    float m_run = -INFINITY, l_run = 0.0f;  // meaningful for t<64 (row t)

    for (int jt = 0; jt < 49; jt++) {
        __syncthreads();
        {
            const int d = t >> 3, seg = (t & 7) * 8;
            const float* src = qb + (size_t)(32 + d) * N_ + jt*64 + seg;
            *(float4*)&k_lds[d*64 + seg]     = *(const float4*)(src);
            *(float4*)&k_lds[d*64 + seg + 4] = *(const float4*)(src + 4);
        }
        __syncthreads();

        float s[4][4];
#pragma unroll
        for (int r = 0; r < 4; r++)
#pragma unroll
            for (int c = 0; c < 4; c++) s[r][c] = 0.0f;
#pragma unroll
        for (int d = 0; d < 32; d++) {
            const float4 qv = *(const float4*)&q_lds[d*64 + i0];
            const float4 kv = *(const float4*)&k_lds[d*64 + j0];
            const float qa[4] = {qv.x, qv.y, qv.z, qv.w};
            const float ka[4] = {kv.x, kv.y, kv.z, kv.w};
#pragma unroll
            for (int r = 0; r < 4; r++)
#pragma unroll
                for (int c = 0; c < 4; c++)
                    s[r][c] = fmaf(qa[r], ka[c], s[r][c]);
        }

        // tile row max
#pragma unroll
        for (int r = 0; r < 4; r++) {
            float lm = fmaxf(fmaxf(s[r][0], s[r][1]), fmaxf(s[r][2], s[r][3]));
            red[tj*64 + i0 + r] = lm;
        }
        __syncthreads();
        if (t < 64) {
            float m_tile = red[t];
            for (int u = 1; u < 16; u++) m_tile = fmaxf(m_tile, red[u*64 + t]);
            const float m_new = fmaxf(m_run, m_tile);
            l_run *= __expf(m_run - m_new);
            m_run = m_new;
            mbc[t] = m_new;
        }
        __syncthreads();
#pragma unroll
        for (int r = 0; r < 4; r++) {
            const float mn = mbc[i0 + r];
            float ps = __expf(s[r][0] - mn) + __expf(s[r][1] - mn)
                     + __expf(s[r][2] - mn) + __expf(s[r][3] - mn);
            red[tj*64 + i0 + r] = ps;
        }
        __syncthreads();
        if (t < 64) {
            float sum = 0.0f;
            for (int u = 0; u < 16; u++) sum += red[u*64 + t];
            l_run += sum;
        }
    }
    if (t < 64) {
        mrow[(size_t)b*N_ + ibt*64 + t] = m_run;
        lrow[(size_t)b*N_ + ibt*64 + t] = 1.0f / l_run;
    }
}

// ---------------------------------------------------------------------------
// Kernel 3: output pass. Recompute S, p = exp(S-m)*rl into LDS [j][i], then
// PV with 8c x 8i register tiles: O[c][i] += vT[j][c] * p[j][i].
// Epilogue: out = gamma*O + x.
// ---------------------------------------------------------------------------
__global__ __launch_bounds__(256) void attn_out_kernel(
    const float* __restrict__ qk, const float* __restrict__ vt,
    const float* __restrict__ mrow, const float* __restrict__ lrow,
    const float* __restrict__ x, const float* __restrict__ gptr,
    float* __restrict__ out)
{
    __shared__ float q_lds[32*64];
    __shared__ float k_lds[32*64];
    __shared__ float p_lds[64*68];  // [j][i], stride 68 (16B-aligned, padded)
    const int ibt = blockIdx.x;
    const int b   = blockIdx.y;
    const int t   = threadIdx.x;
    const int ti = t & 15, tj = t >> 4;
    const int i0 = ti * 4, j0 = tj * 4;
    const int tc = t & 31, tio = t >> 5;
    const int c0 = tc * 8, ip0 = tio * 8;
    const float* qb = qk + (size_t)b * 64 * N_;
    {
        const int d = t >> 3, seg = (t & 7) * 8;
        const float* src = qb + (size_t)d * N_ + ibt*64 + seg;
        *(float4*)&q_lds[d*64 + seg]     = *(const float4*)(src);
        *(float4*)&q_lds[d*64 + seg + 4] = *(const float4*)(src + 4);
    }
    float m_reg[4], rl_reg[4];
#pragma unroll
    for (int r = 0; r < 4; r++) {
        m_reg[r]  = mrow[(size_t)b*N_ + ibt*64 + i0 + r];
        rl_reg[r] = lrow[(size_t)b*N_ + ibt*64 + i0 + r];
    }
    float O[8][8];
#pragma unroll
    for (int ci = 0; ci < 8; ci++)
#pragma unroll
        for (int ii = 0; ii < 8; ii++) O[ci][ii] = 0.0f;

    for (int jt = 0; jt < 49; jt++) {
        __syncthreads();
        {
            const int d = t >> 3, seg = (t & 7) * 8;
            const float* src = qb + (size_t)(32 + d) * N_ + jt*64 + seg;
            *(float4*)&k_lds[d*64 + seg]     = *(const float4*)(src);
            *(float4*)&k_lds[d*64 + seg + 4] = *(const float4*)(src + 4);
        }
        __syncthreads();

        float s[4][4];
#pragma unroll
        for (int r = 0; r < 4; r++)
#pragma unroll
            for (int c = 0; c < 4; c++) s[r][c] = 0.0f;
#pragma unroll
        for (int d = 0; d < 32; d++) {
            const float4 qv = *(const float4*)&q_lds[d*64 + i0];
            const float4 kv = *(const float4*)&k_lds[d*64 + j0];
            const float qa[4] = {qv.x, qv.y, qv.z, qv.w};
            const float ka[4] = {kv.x, kv.y, kv.z, kv.w};
#pragma unroll
            for (int r = 0; r < 4; r++)
#pragma unroll
                for (int c = 0; c < 4; c++)
                    s[r][c] = fmaf(qa[r], ka[c], s[r][c]);
        }

        // p = exp(S - m) * (1/l), store transposed into p_lds[j][i]
#pragma unroll
        for (int jj = 0; jj < 4; jj++) {
            float4 pv;
            pv.x = __expf(s[0][jj] - m_reg[0]) * rl_reg[0];
            pv.y = __expf(s[1][jj] - m_reg[1]) * rl_reg[1];
            pv.z = __expf(s[2][jj] - m_reg[2]) * rl_reg[2];
            pv.w = __expf(s[3][jj] - m_reg[3]) * rl_reg[3];
            *(float4*)&p_lds[(j0 + jj)*68 + i0] = pv;
        }
        __syncthreads();

        // PV: O[c][i] += vT[j][c] * p[j][i]
        const float* vrow = vt + ((size_t)b*N_ + jt*64) * C_ + c0;
#pragma unroll 2
        for (int j = 0; j < 64; j++) {
            const float4 p0 = *(const float4*)&p_lds[j*68 + ip0];
            const float4 p1 = *(const float4*)&p_lds[j*68 + ip0 + 4];
            const float4 v0 = *(const float4*)(vrow + (size_t)j*C_);
            const float4 v1 = *(const float4*)(vrow + (size_t)j*C_ + 4);
            const float pp[8] = {p0.x,p0.y,p0.z,p0.w,p1.x,p1.y,p1.z,p1.w};
            const float vv[8] = {v0.x,v0.y,v0.z,v0.w,v1.x,v1.y,v1.z,v1.w};
#pragma unroll
            for (int ci = 0; ci < 8; ci++)
#pragma unroll
                for (int ii = 0; ii < 8; ii++)
                    O[ci][ii] = fmaf(vv[ci], pp[ii], O[ci][ii]);
        }
    }

    const float gamma = gptr[0];
    const int gi = ibt*64 + ip0;
#pragma unroll
    for (int ci = 0; ci < 8; ci++) {
        const int c = c0 + ci;
        const float* xr = x   + ((size_t)b*C_ + c)*N_ + gi;
        float*       orow = out + ((size_t)b*C_ + c)*N_ + gi;
        const float4 x0 = *(const float4*)(xr);
        const float4 x1 = *(const float4*)(xr + 4);
        float4 o0, o1;
        o0.x = fmaf(gamma, O[ci][0], x0.x);
        o0.y = fmaf(gamma, O[ci][1], x0.y);
        o0.z = fmaf(gamma, O[ci][2], x0.z);
        o0.w = fmaf(gamma, O[ci][3], x0.w);
        o1.x = fmaf(gamma, O[ci][4], x1.x);
        o1.y = fmaf(gamma, O[ci][5], x1.y);
        o1.z = fmaf(gamma, O[ci][6], x1.z);
        o1.w = fmaf(gamma, O[ci][7], x1.w);
        *(float4*)(orow)     = o0;
        *(float4*)(orow + 4) = o1;
    }
}

// ---------------------------------------------------------------------------
extern "C" void kernel_launch(void* const* d_in, const int* in_sizes, int n_in,
                              void* d_out, int out_size, void* d_ws, size_t ws_size,
                              hipStream_t stream)
{
    (void)in_sizes; (void)n_in; (void)out_size; (void)ws_size;
    const float* x  = (const float*)d_in[0];
    const float* wq = (const float*)d_in[1];
    const float* bq = (const float*)d_in[2];
    const float* wk = (const float*)d_in[3];
    const float* bk = (const float*)d_in[4];
    const float* wv = (const float*)d_in[5];
    const float* bv = (const float*)d_in[6];
    const float* gm = (const float*)d_in[7];
    float* out = (float*)d_out;
    float* ws  = (float*)d_ws;   // needs 32.3 MB

    float* qk   = ws + QK_OFF;
    float* vt   = ws + VT_OFF;
    float* mrow = ws + M_OFF;
    float* lrow = ws + L_OFF;

    hipLaunchKernelGGL(conv_qkv_kernel, dim3(10, 7, B_), dim3(448), 0, stream,
                       x, wq, bq, wk, bk, wv, bv, qk, vt);
    hipLaunchKernelGGL(attn_ml_kernel, dim3(49, B_), dim3(256), 0, stream,
                       qk, mrow, lrow);
    hipLaunchKernelGGL(attn_out_kernel, dim3(49, B_), dim3(256), 0, stream,
                       qk, vt, mrow, lrow, x, gm, out);
}

// Round 2
// 1290.057 us; speedup vs baseline: 2.5941x; 2.5941x over previous
//
#include <hip/hip_runtime.h>
#include <math.h>

// Problem constants
#define B_ 8
#define C_ 256
#define H_ 56
#define W_ 56
#define N_ 3136  // 56*56 = 49*64

typedef __attribute__((ext_vector_type(8))) short short8;
typedef __attribute__((ext_vector_type(4))) float f32x4;
#define MFMA16(A, Bf, Cf) __builtin_amdgcn_mfma_f32_16x16x32_bf16((A), (Bf), (Cf), 0, 0, 0)

// -------------------- workspace layout --------------------
// bf16 region (ushort elements):
//   xT_hi : [B][58][64][256]  (padded pixel-major, channel-minor)
//   xT_lo : same
//   A_hi  : [320][2304]  (m = 0..31 q, 32..63 k, 64..319 v; k = s*256+c)
//   A_lo  : [320][2304]
// fp32 region (starts at byte 33,357,824):
//   qk [B][64][N] (q rows 0..31, k rows 32..63), vt [B][N][C], m [B][N], l [B][N]
#define XT_ELEMS (B_*58*64*256)           // 7,602,176
#define A_ELEMS  (320*2304)               // 737,280
#define AHI_OFF  (2*XT_ELEMS)
#define ALO_OFF  (2*XT_ELEMS + A_ELEMS)
#define F32_BYTE_OFF ((size_t)(2*XT_ELEMS + 2*A_ELEMS) * 2)  // 33,357,824
#define QK_OFF 0
#define VT_OFF (B_*64*N_)
#define M_OFF  (VT_OFF + B_*N_*C_)
#define L_OFF  (M_OFF + B_*N_)

__device__ inline unsigned short f2bf(float f) {
    unsigned u = __float_as_uint(f);
    unsigned r = (u + 0x7fffu + ((u >> 16) & 1u)) >> 16;   // RNE
    return (unsigned short)r;
}
__device__ inline float bf2f(unsigned short h) {
    return __uint_as_float(((unsigned)h) << 16);
}

// ---------------------------------------------------------------------------
// Kernel 0: zero the padded xT regions (padding rows/cols must be 0; ws is
// poisoned 0xAA before every launch).
// ---------------------------------------------------------------------------
__global__ __launch_bounds__(256) void zero_pads(uint4* __restrict__ p, int n16)
{
    const int stride = gridDim.x * 256;
    for (int i = blockIdx.x * 256 + threadIdx.x; i < n16; i += stride)
        p[i] = make_uint4(0, 0, 0, 0);
}

// ---------------------------------------------------------------------------
// Kernel 1a: x (fp32 NCHW) -> padded pixel-major bf16 hi/lo.
// grid (cchunk 4, y 56, b 8), block 256. LDS tile transpose.
// ---------------------------------------------------------------------------
__global__ __launch_bounds__(256) void prep_x(
    const float* __restrict__ x,
    unsigned short* __restrict__ xhi, unsigned short* __restrict__ xlo)
{
    __shared__ float xs[64][57];
    const int cc = blockIdx.x, y = blockIdx.y, b = blockIdx.z;
    const int t = threadIdx.x;
    const int c0 = cc * 64;
    for (int idx = t; idx < 64 * 56; idx += 256) {
        const int ch = idx / 56, xc = idx - ch * 56;
        xs[ch][xc] = x[((size_t)(b*C_ + c0 + ch)*H_ + y)*W_ + xc];
    }
    __syncthreads();
    for (int idx = t; idx < 56 * 32; idx += 256) {
        const int xc = idx >> 5, chp = idx & 31;
        const float v0 = xs[2*chp][xc], v1 = xs[2*chp + 1][xc];
        const unsigned short h0 = f2bf(v0), h1 = f2bf(v1);
        const unsigned short l0 = f2bf(v0 - bf2f(h0));
        const unsigned short l1 = f2bf(v1 - bf2f(h1));
        const size_t o = ((size_t)(b*58 + y + 1) * 64 + (xc + 1)) * 256 + c0 + 2*chp;
        *(unsigned*)(xhi + o) = (unsigned)h0 | ((unsigned)h1 << 16);
        *(unsigned*)(xlo + o) = (unsigned)l0 | ((unsigned)l1 << 16);
    }
}

// ---------------------------------------------------------------------------
// Kernel 1b: weights -> A_hi/A_lo [320][2304], k = s*256 + c.
// ---------------------------------------------------------------------------
__global__ __launch_bounds__(256) void prep_w(
    const float* __restrict__ wq, const float* __restrict__ wk,
    const float* __restrict__ wv,
    unsigned short* __restrict__ Ahi, unsigned short* __restrict__ Alo)
{
    const int g = blockIdx.x * 256 + threadIdx.x;
    if (g >= 320 * 2304) return;
    const int m = g / 2304, k = g - m * 2304;
    const int s = k >> 8, c = k & 255;
    float w;
    if (m < 32)      w = wq[((size_t)m*C_ + c)*9 + s];
    else if (m < 64) w = wk[((size_t)(m-32)*C_ + c)*9 + s];
    else             w = wv[((size_t)(m-64)*C_ + c)*9 + s];
    const unsigned short h = f2bf(w);
    Ahi[g] = h;
    Alo[g] = f2bf(w - bf2f(h));
}

// ---------------------------------------------------------------------------
// Kernel 2: implicit-GEMM conv via MFMA. grid (y 56, b 8), block 256 = 4 waves.
// Wave w owns m-tiles: {w} (q/k, bf16x3) and {4+4w..7+4w} (v, bf16).
// All 4 n-tiles (64 pixels of output row y) per wave. No LDS.
// q/k written fp32 [B][64][N]; v written fp32 transposed [B][N][C].
// ---------------------------------------------------------------------------
__global__ __launch_bounds__(256) void conv_mfma(
    const unsigned short* __restrict__ xhi, const unsigned short* __restrict__ xlo,
    const unsigned short* __restrict__ Ahi, const unsigned short* __restrict__ Alo,
    const float* __restrict__ bq, const float* __restrict__ bk,
    const float* __restrict__ bv,
    float* __restrict__ qk, float* __restrict__ vt)
{
    const int y = blockIdx.x, b = blockIdx.y;
    const int t = threadIdx.x;
    const int w = t >> 6, L = t & 63;
    const int ln = L & 15, quad = L >> 4;

    f32x4 acc[5][4];
#pragma unroll
    for (int i = 0; i < 5; i++)
#pragma unroll
        for (int nt = 0; nt < 4; nt++) acc[i][nt] = (f32x4)0.0f;

    const size_t aq_row = (size_t)(w*16 + ln) * 2304 + quad*8;

#pragma unroll
    for (int s = 0; s < 9; s++) {
        const int dy = s / 3 - 1, dx = s % 3 - 1;
        const size_t rowbase = ((size_t)(b*58) + (y + dy + 1)) * (64*256);
        const size_t colbase = rowbase + (size_t)(ln + dx + 1) * 256 + quad*8;
        for (int cb = 0; cb < 8; cb++) {
            const int c0 = cb * 32;
            const int kk = s*256 + c0;
            short8 Bh[4], Bl[4];
            const size_t ba = colbase + c0;
#pragma unroll
            for (int nt = 0; nt < 4; nt++) {
                Bh[nt] = *(const short8*)(xhi + ba + nt*(16*256));
                Bl[nt] = *(const short8*)(xlo + ba + nt*(16*256));
            }
            // q/k tile: bf16x3
            const short8 Aq  = *(const short8*)(Ahi + aq_row + kk);
            const short8 Aql = *(const short8*)(Alo + aq_row + kk);
#pragma unroll
            for (int nt = 0; nt < 4; nt++) {
                acc[0][nt] = MFMA16(Aq,  Bh[nt], acc[0][nt]);
                acc[0][nt] = MFMA16(Aq,  Bl[nt], acc[0][nt]);
                acc[0][nt] = MFMA16(Aql, Bh[nt], acc[0][nt]);
            }
            // v tiles: plain bf16
#pragma unroll
            for (int i = 0; i < 4; i++) {
                const int m0 = 64*(1 + w) + 16*i;
                const short8 Av = *(const short8*)(Ahi + (size_t)(m0 + ln)*2304 + kk + quad*8);
#pragma unroll
                for (int nt = 0; nt < 4; nt++)
                    acc[1+i][nt] = MFMA16(Av, Bh[nt], acc[1+i][nt]);
            }
        }
    }

    // epilogue: C/D layout col = lane&15 (pixel), row = quad*4 + reg (channel)
#pragma unroll
    for (int nt = 0; nt < 4; nt++) {
        const int n = nt*16 + ln;
        if (n >= 56) continue;
        const int pix = y*56 + n;
        // q/k rows
#pragma unroll
        for (int r = 0; r < 4; r++) {
            const int m = w*16 + quad*4 + r;
            const float bias = (m < 32) ? bq[m] : bk[m - 32];
            qk[((size_t)b*64 + m)*N_ + pix] = acc[0][nt][r] + bias;
        }
        // v channels (float4 per tile)
        float* vdst = vt + ((size_t)b*N_ + pix) * C_;
#pragma unroll
        for (int i = 0; i < 4; i++) {
            const int cbase = 64*w + 16*i + quad*4;
            const float4 bb = *(const float4*)(bv + cbase);
            float4 o;
            o.x = acc[1+i][nt][0] + bb.x;
            o.y = acc[1+i][nt][1] + bb.y;
            o.z = acc[1+i][nt][2] + bb.z;
            o.w = acc[1+i][nt][3] + bb.w;
            *(float4*)(vdst + cbase) = o;
        }
    }
}

// ---------------------------------------------------------------------------
// Kernel 3: softmax statistics pass (unchanged from R1).
// ---------------------------------------------------------------------------
__global__ __launch_bounds__(256) void attn_ml_kernel(
    const float* __restrict__ qk, float* __restrict__ mrow, float* __restrict__ lrow)
{
    __shared__ float q_lds[32*64];
    __shared__ float k_lds[32*64];
    __shared__ float red[16*64];
    __shared__ float mbc[64];
    const int ibt = blockIdx.x;
    const int b   = blockIdx.y;
    const int t   = threadIdx.x;
    const int ti = t & 15, tj = t >> 4;
    const int i0 = ti * 4, j0 = tj * 4;
    const float* qb = qk + (size_t)b * 64 * N_;
    {
        const int d = t >> 3, seg = (t & 7) * 8;
        const float* src = qb + (size_t)d * N_ + ibt*64 + seg;
        *(float4*)&q_lds[d*64 + seg]     = *(const float4*)(src);
        *(float4*)&q_lds[d*64 + seg + 4] = *(const float4*)(src + 4);
    }
    float m_run = -INFINITY, l_run = 0.0f;

    for (int jt = 0; jt < 49; jt++) {
        __syncthreads();
        {
            const int d = t >> 3, seg = (t & 7) * 8;
            const float* src = qb + (size_t)(32 + d) * N_ + jt*64 + seg;
            *(float4*)&k_lds[d*64 + seg]     = *(const float4*)(src);
            *(float4*)&k_lds[d*64 + seg + 4] = *(const float4*)(src + 4);
        }
        __syncthreads();

        float s[4][4];
#pragma unroll
        for (int r = 0; r < 4; r++)
#pragma unroll
            for (int c = 0; c < 4; c++) s[r][c] = 0.0f;
#pragma unroll
        for (int d = 0; d < 32; d++) {
            const float4 qv = *(const float4*)&q_lds[d*64 + i0];
            const float4 kv = *(const float4*)&k_lds[d*64 + j0];
            const float qa[4] = {qv.x, qv.y, qv.z, qv.w};
            const float ka[4] = {kv.x, kv.y, kv.z, kv.w};
#pragma unroll
            for (int r = 0; r < 4; r++)
#pragma unroll
                for (int c = 0; c < 4; c++)
                    s[r][c] = fmaf(qa[r], ka[c], s[r][c]);
        }

#pragma unroll
        for (int r = 0; r < 4; r++) {
            float lm = fmaxf(fmaxf(s[r][0], s[r][1]), fmaxf(s[r][2], s[r][3]));
            red[tj*64 + i0 + r] = lm;
        }
        __syncthreads();
        if (t < 64) {
            float m_tile = red[t];
            for (int u = 1; u < 16; u++) m_tile = fmaxf(m_tile, red[u*64 + t]);
            const float m_new = fmaxf(m_run, m_tile);
            l_run *= __expf(m_run - m_new);
            m_run = m_new;
            mbc[t] = m_new;
        }
        __syncthreads();
#pragma unroll
        for (int r = 0; r < 4; r++) {
            const float mn = mbc[i0 + r];
            float ps = __expf(s[r][0] - mn) + __expf(s[r][1] - mn)
                     + __expf(s[r][2] - mn) + __expf(s[r][3] - mn);
            red[tj*64 + i0 + r] = ps;
        }
        __syncthreads();
        if (t < 64) {
            float sum = 0.0f;
            for (int u = 0; u < 16; u++) sum += red[u*64 + t];
            l_run += sum;
        }
    }
    if (t < 64) {
        mrow[(size_t)b*N_ + ibt*64 + t] = m_run;
        lrow[(size_t)b*N_ + ibt*64 + t] = 1.0f / l_run;
    }
}

// ---------------------------------------------------------------------------
// Kernel 4: output pass (unchanged from R1).
// ---------------------------------------------------------------------------
__global__ __launch_bounds__(256) void attn_out_kernel(
    const float* __restrict__ qk, const float* __restrict__ vt,
    const float* __restrict__ mrow, const float* __restrict__ lrow,
    const float* __restrict__ x, const float* __restrict__ gptr,
    float* __restrict__ out)
{
    __shared__ float q_lds[32*64];
    __shared__ float k_lds[32*64];
    __shared__ float p_lds[64*68];
    const int ibt = blockIdx.x;
    const int b   = blockIdx.y;
    const int t   = threadIdx.x;
    const int ti = t & 15, tj = t >> 4;
    const int i0 = ti * 4, j0 = tj * 4;
    const int tc = t & 31, tio = t >> 5;
    const int c0 = tc * 8, ip0 = tio * 8;
    const float* qb = qk + (size_t)b * 64 * N_;
    {
        const int d = t >> 3, seg = (t & 7) * 8;
        const float* src = qb + (size_t)d * N_ + ibt*64 + seg;
        *(float4*)&q_lds[d*64 + seg]     = *(const float4*)(src);
        *(float4*)&q_lds[d*64 + seg + 4] = *(const float4*)(src + 4);
    }
    float m_reg[4], rl_reg[4];
#pragma unroll
    for (int r = 0; r < 4; r++) {
        m_reg[r]  = mrow[(size_t)b*N_ + ibt*64 + i0 + r];
        rl_reg[r] = lrow[(size_t)b*N_ + ibt*64 + i0 + r];
    }
    float O[8][8];
#pragma unroll
    for (int ci = 0; ci < 8; ci++)
#pragma unroll
        for (int ii = 0; ii < 8; ii++) O[ci][ii] = 0.0f;

    for (int jt = 0; jt < 49; jt++) {
        __syncthreads();
        {
            const int d = t >> 3, seg = (t & 7) * 8;
            const float* src = qb + (size_t)(32 + d) * N_ + jt*64 + seg;
            *(float4*)&k_lds[d*64 + seg]     = *(const float4*)(src);
            *(float4*)&k_lds[d*64 + seg + 4] = *(const float4*)(src + 4);
        }
        __syncthreads();

        float s[4][4];
#pragma unroll
        for (int r = 0; r < 4; r++)
#pragma unroll
            for (int c = 0; c < 4; c++) s[r][c] = 0.0f;
#pragma unroll
        for (int d = 0; d < 32; d++) {
            const float4 qv = *(const float4*)&q_lds[d*64 + i0];
            const float4 kv = *(const float4*)&k_lds[d*64 + j0];
            const float qa[4] = {qv.x, qv.y, qv.z, qv.w};
            const float ka[4] = {kv.x, kv.y, kv.z, kv.w};
#pragma unroll
            for (int r = 0; r < 4; r++)
#pragma unroll
                for (int c = 0; c < 4; c++)
                    s[r][c] = fmaf(qa[r], ka[c], s[r][c]);
        }

#pragma unroll
        for (int jj = 0; jj < 4; jj++) {
            float4 pv;
            pv.x = __expf(s[0][jj] - m_reg[0]) * rl_reg[0];
            pv.y = __expf(s[1][jj] - m_reg[1]) * rl_reg[1];
            pv.z = __expf(s[2][jj] - m_reg[2]) * rl_reg[2];
            pv.w = __expf(s[3][jj] - m_reg[3]) * rl_reg[3];
            *(float4*)&p_lds[(j0 + jj)*68 + i0] = pv;
        }
        __syncthreads();

        const float* vrow = vt + ((size_t)b*N_ + jt*64) * C_ + c0;
#pragma unroll 2
        for (int j = 0; j < 64; j++) {
            const float4 p0 = *(const float4*)&p_lds[j*68 + ip0];
            const float4 p1 = *(const float4*)&p_lds[j*68 + ip0 + 4];
            const float4 v0 = *(const float4*)(vrow + (size_t)j*C_);
            const float4 v1 = *(const float4*)(vrow + (size_t)j*C_ + 4);
            const float pp[8] = {p0.x,p0.y,p0.z,p0.w,p1.x,p1.y,p1.z,p1.w};
            const float vv[8] = {v0.x,v0.y,v0.z,v0.w,v1.x,v1.y,v1.z,v1.w};
#pragma unroll
            for (int ci = 0; ci < 8; ci++)
#pragma unroll
                for (int ii = 0; ii < 8; ii++)
                    O[ci][ii] = fmaf(vv[ci], pp[ii], O[ci][ii]);
        }
    }

    const float gamma = gptr[0];
    const int gi = ibt*64 + ip0;
#pragma unroll
    for (int ci = 0; ci < 8; ci++) {
        const int c = c0 + ci;
        const float* xr = x   + ((size_t)b*C_ + c)*N_ + gi;
        float*       orow = out + ((size_t)b*C_ + c)*N_ + gi;
        const float4 x0 = *(const float4*)(xr);
        const float4 x1 = *(const float4*)(xr + 4);
        float4 o0, o1;
        o0.x = fmaf(gamma, O[ci][0], x0.x);
        o0.y = fmaf(gamma, O[ci][1], x0.y);
        o0.z = fmaf(gamma, O[ci][2], x0.z);
        o0.w = fmaf(gamma, O[ci][3], x0.w);
        o1.x = fmaf(gamma, O[ci][4], x1.x);
        o1.y = fmaf(gamma, O[ci][5], x1.y);
        o1.z = fmaf(gamma, O[ci][6], x1.z);
        o1.w = fmaf(gamma, O[ci][7], x1.w);
        *(float4*)(orow)     = o0;
        *(float4*)(orow + 4) = o1;
    }
}

// ---------------------------------------------------------------------------
extern "C" void kernel_launch(void* const* d_in, const int* in_sizes, int n_in,
                              void* d_out, int out_size, void* d_ws, size_t ws_size,
                              hipStream_t stream)
{
    (void)in_sizes; (void)n_in; (void)out_size; (void)ws_size;
    const float* x  = (const float*)d_in[0];
    const float* wq = (const float*)d_in[1];
    const float* bq = (const float*)d_in[2];
    const float* wk = (const float*)d_in[3];
    const float* bk = (const float*)d_in[4];
    const float* wv = (const float*)d_in[5];
    const float* bv = (const float*)d_in[6];
    const float* gm = (const float*)d_in[7];
    float* out = (float*)d_out;

    unsigned short* bfbase = (unsigned short*)d_ws;
    unsigned short* xhi = bfbase;
    unsigned short* xlo = bfbase + XT_ELEMS;
    unsigned short* Ahi = bfbase + AHI_OFF;
    unsigned short* Alo = bfbase + ALO_OFF;
    float* f32 = (float*)((char*)d_ws + F32_BYTE_OFF);
    float* qk   = f32 + QK_OFF;
    float* vt   = f32 + VT_OFF;
    float* mrow = f32 + M_OFF;
    float* lrow = f32 + L_OFF;

    // zero the padded xT regions (2*XT_ELEMS ushorts = 1,900,544 uint4)
    hipLaunchKernelGGL(zero_pads, dim3(1024), dim3(256), 0, stream,
                       (uint4*)d_ws, (2*XT_ELEMS*2)/16);
    hipLaunchKernelGGL(prep_x, dim3(4, 56, 8), dim3(256), 0, stream, x, xhi, xlo);
    hipLaunchKernelGGL(prep_w, dim3(2880), dim3(256), 0, stream, wq, wk, wv, Ahi, Alo);
    hipLaunchKernelGGL(conv_mfma, dim3(56, 8), dim3(256), 0, stream,
                       xhi, xlo, Ahi, Alo, bq, bk, bv, qk, vt);
    hipLaunchKernelGGL(attn_ml_kernel, dim3(49, B_), dim3(256), 0, stream,
                       qk, mrow, lrow);
    hipLaunchKernelGGL(attn_out_kernel, dim3(49, B_), dim3(256), 0, stream,
                       qk, vt, mrow, lrow, x, gm, out);
}

// Round 3
// 694.948 us; speedup vs baseline: 4.8155x; 1.8563x over previous
//
#include <hip/hip_runtime.h>
#include <math.h>

// Problem constants
#define B_ 8
#define C_ 256
#define H_ 56
#define W_ 56
#define N_ 3136  // 56*56 = 49*64

typedef __attribute__((ext_vector_type(8))) short short8;
typedef __attribute__((ext_vector_type(4))) short short4v;
typedef __attribute__((ext_vector_type(4))) float f32x4;
typedef __attribute__((ext_vector_type(16))) float f32x16;
typedef __attribute__((ext_vector_type(4))) unsigned short u16x4;
#define MFMA16(A, Bf, Cf) __builtin_amdgcn_mfma_f32_16x16x32_bf16((A), (Bf), (Cf), 0, 0, 0)
#define MFMA32(A, Bf, Cf) __builtin_amdgcn_mfma_f32_32x32x16_bf16((A), (Bf), (Cf), 0, 0, 0)

// -------------------- workspace layout (ushort units) --------------------
// xhi [B][58][64][256], xlo same  (padded pixel-major x, bf16 hi/lo)
// Ahi [320][2304], Alo same       (conv weights, k = s*256+c)
// qkt_hi [B][N][64], qkt_lo same  (d 0..31 = q, 32..63 = k; fragment-ready)
// vbf [B][C][N]                   (v bf16, PV A-operand layout)
// fp32: mrow [B][N], lrow [B][N]
#define XT_ELEMS (B_*58*64*256)           // 7,602,176
#define A_ELEMS  (320*2304)               // 737,280
#define AHI_OFF  (2*XT_ELEMS)
#define ALO_OFF  (AHI_OFF + A_ELEMS)
#define QKT_HI_OFF (ALO_OFF + A_ELEMS)    // 16,678,912
#define QKT_ELEMS  (B_*N_*64)             // 1,605,632
#define QKT_LO_OFF (QKT_HI_OFF + QKT_ELEMS)
#define VBF_OFF    (QKT_LO_OFF + QKT_ELEMS)
#define VBF_ELEMS  (B_*C_*N_)             // 6,422,528
#define F32_BYTE_OFF ((size_t)(VBF_OFF + VBF_ELEMS) * 2)   // 52,625,408 (16B aligned)
#define M_OFF 0
#define L_OFF (B_*N_)

__device__ inline unsigned short f2bf(float f) {
    unsigned u = __float_as_uint(f);
    unsigned r = (u + 0x7fffu + ((u >> 16) & 1u)) >> 16;   // RNE
    return (unsigned short)r;
}
__device__ inline float bf2f(unsigned short h) {
    return __uint_as_float(((unsigned)h) << 16);
}

// ---------------------------------------------------------------------------
// Kernel 0: zero the padded x regions (ws is poisoned 0xAA each launch).
// ---------------------------------------------------------------------------
__global__ __launch_bounds__(256) void zero_pads(uint4* __restrict__ p, int n16)
{
    const int stride = gridDim.x * 256;
    for (int i = blockIdx.x * 256 + threadIdx.x; i < n16; i += stride)
        p[i] = make_uint4(0, 0, 0, 0);
}

// ---------------------------------------------------------------------------
// Kernel 1a: x (fp32 NCHW) -> padded pixel-major bf16 hi/lo.
// ---------------------------------------------------------------------------
__global__ __launch_bounds__(256) void prep_x(
    const float* __restrict__ x,
    unsigned short* __restrict__ xhi, unsigned short* __restrict__ xlo)
{
    __shared__ float xs[64][57];
    const int cc = blockIdx.x, y = blockIdx.y, b = blockIdx.z;
    const int t = threadIdx.x;
    const int c0 = cc * 64;
    for (int idx = t; idx < 64 * 56; idx += 256) {
        const int ch = idx / 56, xc = idx - ch * 56;
        xs[ch][xc] = x[((size_t)(b*C_ + c0 + ch)*H_ + y)*W_ + xc];
    }
    __syncthreads();
    for (int idx = t; idx < 56 * 32; idx += 256) {
        const int xc = idx >> 5, chp = idx & 31;
        const float v0 = xs[2*chp][xc], v1 = xs[2*chp + 1][xc];
        const unsigned short h0 = f2bf(v0), h1 = f2bf(v1);
        const unsigned short l0 = f2bf(v0 - bf2f(h0));
        const unsigned short l1 = f2bf(v1 - bf2f(h1));
        const size_t o = ((size_t)(b*58 + y + 1) * 64 + (xc + 1)) * 256 + c0 + 2*chp;
        *(unsigned*)(xhi + o) = (unsigned)h0 | ((unsigned)h1 << 16);
        *(unsigned*)(xlo + o) = (unsigned)l0 | ((unsigned)l1 << 16);
    }
}

// ---------------------------------------------------------------------------
// Kernel 1b: weights -> A_hi/A_lo [320][2304], k = s*256 + c.
// ---------------------------------------------------------------------------
__global__ __launch_bounds__(256) void prep_w(
    const float* __restrict__ wq, const float* __restrict__ wk,
    const float* __restrict__ wv,
    unsigned short* __restrict__ Ahi, unsigned short* __restrict__ Alo)
{
    const int g = blockIdx.x * 256 + threadIdx.x;
    if (g >= 320 * 2304) return;
    const int m = g / 2304, k = g - m * 2304;
    const int s = k >> 8, c = k & 255;
    float w;
    if (m < 32)      w = wq[((size_t)m*C_ + c)*9 + s];
    else if (m < 64) w = wk[((size_t)(m-32)*C_ + c)*9 + s];
    else             w = wv[((size_t)(m-64)*C_ + c)*9 + s];
    const unsigned short h = f2bf(w);
    Ahi[g] = h;
    Alo[g] = f2bf(w - bf2f(h));
}

// ---------------------------------------------------------------------------
// Kernel 2: implicit-GEMM conv via MFMA. grid (y 56, b 8), block 256 = 4 waves.
// Epilogue writes q/k as bf16 hi/lo [B][N][64] and v as bf16 [B][C][N].
// ---------------------------------------------------------------------------
__global__ __launch_bounds__(256) void conv_mfma(
    const unsigned short* __restrict__ xhi, const unsigned short* __restrict__ xlo,
    const unsigned short* __restrict__ Ahi, const unsigned short* __restrict__ Alo,
    const float* __restrict__ bq, const float* __restrict__ bk,
    const float* __restrict__ bv,
    unsigned short* __restrict__ qkt_hi, unsigned short* __restrict__ qkt_lo,
    unsigned short* __restrict__ vbf)
{
    const int y = blockIdx.x, b = blockIdx.y;
    const int t = threadIdx.x;
    const int w = t >> 6, L = t & 63;
    const int ln = L & 15, quad = L >> 4;

    f32x4 acc[5][4];
#pragma unroll
    for (int i = 0; i < 5; i++)
#pragma unroll
        for (int nt = 0; nt < 4; nt++) acc[i][nt] = (f32x4)0.0f;

    const size_t aq_row = (size_t)(w*16 + ln) * 2304 + quad*8;

#pragma unroll
    for (int s = 0; s < 9; s++) {
        const int dy = s / 3 - 1, dx = s % 3 - 1;
        const size_t rowbase = ((size_t)(b*58) + (y + dy + 1)) * (64*256);
        const size_t colbase = rowbase + (size_t)(ln + dx + 1) * 256 + quad*8;
        for (int cb = 0; cb < 8; cb++) {
            const int c0 = cb * 32;
            const int kk = s*256 + c0;
            short8 Bh[4], Bl[4];
            const size_t ba = colbase + c0;
#pragma unroll
            for (int nt = 0; nt < 4; nt++) {
                Bh[nt] = *(const short8*)(xhi + ba + nt*(16*256));
                Bl[nt] = *(const short8*)(xlo + ba + nt*(16*256));
            }
            const short8 Aq  = *(const short8*)(Ahi + aq_row + kk);
            const short8 Aql = *(const short8*)(Alo + aq_row + kk);
#pragma unroll
            for (int nt = 0; nt < 4; nt++) {
                acc[0][nt] = MFMA16(Aq,  Bh[nt], acc[0][nt]);
                acc[0][nt] = MFMA16(Aq,  Bl[nt], acc[0][nt]);
                acc[0][nt] = MFMA16(Aql, Bh[nt], acc[0][nt]);
            }
#pragma unroll
            for (int i = 0; i < 4; i++) {
                const int m0 = 64*(1 + w) + 16*i;
                const short8 Av = *(const short8*)(Ahi + (size_t)(m0 + ln)*2304 + kk + quad*8);
#pragma unroll
                for (int nt = 0; nt < 4; nt++)
                    acc[1+i][nt] = MFMA16(Av, Bh[nt], acc[1+i][nt]);
            }
        }
    }

    // epilogue: C/D layout col = lane&15 (pixel), row = quad*4 + r
#pragma unroll
    for (int nt = 0; nt < 4; nt++) {
        const int n = nt*16 + ln;
        if (n >= 56) continue;
        const int pix = y*56 + n;
        // q/k -> bf16 hi/lo, packed 4 channels per 8B store
        {
            u16x4 hi4, lo4;
#pragma unroll
            for (int r = 0; r < 4; r++) {
                const int m = w*16 + quad*4 + r;
                const float bias = (m < 32) ? bq[m] : bk[m - 32];
                const float val = acc[0][nt][r] + bias;
                const unsigned short h = f2bf(val);
                hi4[r] = h;
                lo4[r] = f2bf(val - bf2f(h));
            }
            const size_t o = (size_t)(b*N_ + pix)*64 + w*16 + quad*4;
            *(u16x4*)(qkt_hi + o) = hi4;
            *(u16x4*)(qkt_lo + o) = lo4;
        }
        // v -> bf16 [B][C][N]
#pragma unroll
        for (int i = 0; i < 4; i++) {
            const int cbase = 64*w + 16*i + quad*4;
            const float4 bb = *(const float4*)(bv + cbase);
            const float vv[4] = {acc[1+i][nt][0] + bb.x, acc[1+i][nt][1] + bb.y,
                                 acc[1+i][nt][2] + bb.z, acc[1+i][nt][3] + bb.w};
#pragma unroll
            for (int r = 0; r < 4; r++)
                vbf[(size_t)(b*C_ + cbase + r)*N_ + pix] = f2bf(vv[r]);
        }
    }
}

// ---------------------------------------------------------------------------
// Kernel 3: softmax statistics via MFMA (bf16x3 S). grid 392 (b = id&7),
// block 256 = 4 waves; wave w owns i-rows [it*64+w*16, +16), all j.
// ---------------------------------------------------------------------------
__global__ __launch_bounds__(256) void attn_ml2(
    const unsigned short* __restrict__ qkt_hi, const unsigned short* __restrict__ qkt_lo,
    float* __restrict__ mrow, float* __restrict__ lrow)
{
    const int bid = blockIdx.x;
    const int b = bid & 7, it = bid >> 3;
    const int t = threadIdx.x;
    const int w = t >> 6, L = t & 63;
    const int ln = L & 15, quad = L >> 4;

    // q A-frags (hi/lo): row i = it*64 + w*16 + ln, k = d = quad*8..+7
    const size_t qoff = (size_t)(b*N_ + it*64 + w*16 + ln)*64 + quad*8;
    const short8 qh = *(const short8*)(qkt_hi + qoff);
    const short8 ql = *(const short8*)(qkt_lo + qoff);

    float m_run[4], l_run[4];
#pragma unroll
    for (int r = 0; r < 4; r++) { m_run[r] = -INFINITY; l_run[r] = 0.0f; }

    for (int jt = 0; jt < 49; jt++) {
        f32x4 sacc[4];
#pragma unroll
        for (int tj = 0; tj < 4; tj++) {
            const size_t koff = (size_t)(b*N_ + jt*64 + tj*16 + ln)*64 + 32 + quad*8;
            const short8 kh = *(const short8*)(qkt_hi + koff);
            const short8 kl = *(const short8*)(qkt_lo + koff);
            f32x4 a = (f32x4)0.0f;
            a = MFMA16(qh, kh, a);
            a = MFMA16(qh, kl, a);
            a = MFMA16(ql, kh, a);
            sacc[tj] = a;
        }
#pragma unroll
        for (int r = 0; r < 4; r++) {
            float tm = fmaxf(fmaxf(sacc[0][r], sacc[1][r]), fmaxf(sacc[2][r], sacc[3][r]));
            tm = fmaxf(tm, __shfl_xor(tm, 1));
            tm = fmaxf(tm, __shfl_xor(tm, 2));
            tm = fmaxf(tm, __shfl_xor(tm, 4));
            tm = fmaxf(tm, __shfl_xor(tm, 8));
            const float m_new = fmaxf(m_run[r], tm);
            float ps = __expf(sacc[0][r] - m_new) + __expf(sacc[1][r] - m_new)
                     + __expf(sacc[2][r] - m_new) + __expf(sacc[3][r] - m_new);
            ps += __shfl_xor(ps, 1);
            ps += __shfl_xor(ps, 2);
            ps += __shfl_xor(ps, 4);
            ps += __shfl_xor(ps, 8);
            l_run[r] = l_run[r] * __expf(m_run[r] - m_new) + ps;
            m_run[r] = m_new;
        }
    }
    if (ln == 0) {
#pragma unroll
        for (int r = 0; r < 4; r++) {
            const int row = it*64 + w*16 + quad*4 + r;
            mrow[(size_t)b*N_ + row] = m_run[r];
            lrow[(size_t)b*N_ + row] = 1.0f / l_run[r];
        }
    }
}

// ---------------------------------------------------------------------------
// Kernel 4: output pass. Recompute S (bitwise same as pass 1), P=exp(S-m)*rl
// -> bf16 LDS [i][j] stride 68, PV via mfma 32x32x16. grid 392, block 512.
// Wave w: S-tiles (ti=w&3, tj=2*(w>>2)+{0,1}); PV c-tile = w*32, i-tiles 0,1.
// ---------------------------------------------------------------------------
__global__ __launch_bounds__(512) void attn_out2(
    const unsigned short* __restrict__ qkt_hi, const unsigned short* __restrict__ qkt_lo,
    const unsigned short* __restrict__ vbf,
    const float* __restrict__ mrow, const float* __restrict__ lrow,
    const float* __restrict__ x, const float* __restrict__ gptr,
    float* __restrict__ out)
{
    __shared__ unsigned short P[64*68];   // 8704 B, stride 68 (2-way banks, 8B aligned)
    const int bid = blockIdx.x;
    const int b = bid & 7, it = bid >> 3;
    const int t = threadIdx.x;
    const int w = t >> 6, L = t & 63;
    const int ln = L & 15, quad = L >> 4;
    const int ti = w & 3, tjb = (w >> 2) * 2;
    const int l32 = L & 31, h32 = L >> 5;

    // q A-frags for this wave's i-rows
    const size_t qoff = (size_t)(b*N_ + it*64 + ti*16 + ln)*64 + quad*8;
    const short8 qh = *(const short8*)(qkt_hi + qoff);
    const short8 ql = *(const short8*)(qkt_lo + qoff);

    float mr[4], rl[4];
#pragma unroll
    for (int r = 0; r < 4; r++) {
        const int row = it*64 + ti*16 + quad*4 + r;
        mr[r] = mrow[(size_t)b*N_ + row];
        rl[r] = lrow[(size_t)b*N_ + row];
    }

    f32x16 O0 = (f32x16)0.0f, O1 = (f32x16)0.0f;
    const unsigned short* vrow = vbf + (size_t)(b*C_ + w*32 + l32) * N_;

    for (int jt = 0; jt < 49; jt++) {
        f32x4 sacc[2];
#pragma unroll
        for (int u = 0; u < 2; u++) {
            const int tj = tjb + u;
            const size_t koff = (size_t)(b*N_ + jt*64 + tj*16 + ln)*64 + 32 + quad*8;
            const short8 kh = *(const short8*)(qkt_hi + koff);
            const short8 kl = *(const short8*)(qkt_lo + koff);
            f32x4 a = (f32x4)0.0f;
            a = MFMA16(qh, kh, a);
            a = MFMA16(qh, kl, a);
            a = MFMA16(ql, kh, a);
            sacc[u] = a;
        }
        if (jt) __syncthreads();   // all waves done reading previous P
#pragma unroll
        for (int u = 0; u < 2; u++) {
            const int tj = tjb + u;
#pragma unroll
            for (int r = 0; r < 4; r++) {
                const float p = __expf(sacc[u][r] - mr[r]) * rl[r];
                P[(ti*16 + quad*4 + r)*68 + tj*16 + ln] = f2bf(p);
            }
        }
        __syncthreads();

        const unsigned short* vj = vrow + jt*64;
#pragma unroll
        for (int s = 0; s < 4; s++) {
            const short8 Af = *(const short8*)(vj + s*16 + h32*8);
            short8 B0, B1;
            {
                const unsigned short* p0 = &P[(l32)*68 + s*16 + h32*8];
                *(short4v*)&B0       = *(const short4v*)(p0);
                *((short4v*)&B0 + 1) = *(const short4v*)(p0 + 4);
                const unsigned short* p1 = &P[(32 + l32)*68 + s*16 + h32*8];
                *(short4v*)&B1       = *(const short4v*)(p1);
                *((short4v*)&B1 + 1) = *(const short4v*)(p1 + 4);
            }
            O0 = MFMA32(Af, B0, O0);
            O1 = MFMA32(Af, B1, O1);
        }
    }

    const float gamma = gptr[0];
#pragma unroll
    for (int itile = 0; itile < 2; itile++) {
        const f32x16 Ot = itile ? O1 : O0;
        const int pix = it*64 + itile*32 + l32;
#pragma unroll
        for (int reg = 0; reg < 16; reg++) {
            const int c = w*32 + (reg & 3) + 8*(reg >> 2) + 4*h32;
            const size_t idx = (size_t)(b*C_ + c)*N_ + pix;
            out[idx] = fmaf(gamma, Ot[reg], x[idx]);
        }
    }
}

// ---------------------------------------------------------------------------
extern "C" void kernel_launch(void* const* d_in, const int* in_sizes, int n_in,
                              void* d_out, int out_size, void* d_ws, size_t ws_size,
                              hipStream_t stream)
{
    (void)in_sizes; (void)n_in; (void)out_size; (void)ws_size;
    const float* x  = (const float*)d_in[0];
    const float* wq = (const float*)d_in[1];
    const float* bq = (const float*)d_in[2];
    const float* wk = (const float*)d_in[3];
    const float* bk = (const float*)d_in[4];
    const float* wv = (const float*)d_in[5];
    const float* bv = (const float*)d_in[6];
    const float* gm = (const float*)d_in[7];
    float* out = (float*)d_out;

    unsigned short* u = (unsigned short*)d_ws;
    unsigned short* xhi = u;
    unsigned short* xlo = u + XT_ELEMS;
    unsigned short* Ahi = u + AHI_OFF;
    unsigned short* Alo = u + ALO_OFF;
    unsigned short* qkt_hi = u + QKT_HI_OFF;
    unsigned short* qkt_lo = u + QKT_LO_OFF;
    unsigned short* vbf = u + VBF_OFF;
    float* f32 = (float*)((char*)d_ws + F32_BYTE_OFF);
    float* mrowp = f32 + M_OFF;
    float* lrowp = f32 + L_OFF;

    hipLaunchKernelGGL(zero_pads, dim3(1024), dim3(256), 0, stream,
                       (uint4*)d_ws, (2*XT_ELEMS*2)/16);
    hipLaunchKernelGGL(prep_x, dim3(4, 56, 8), dim3(256), 0, stream, x, xhi, xlo);
    hipLaunchKernelGGL(prep_w, dim3(2880), dim3(256), 0, stream, wq, wk, wv, Ahi, Alo);
    hipLaunchKernelGGL(conv_mfma, dim3(56, 8), dim3(256), 0, stream,
                       xhi, xlo, Ahi, Alo, bq, bk, bv, qkt_hi, qkt_lo, vbf);
    hipLaunchKernelGGL(attn_ml2, dim3(49*8), dim3(256), 0, stream,
                       qkt_hi, qkt_lo, mrowp, lrowp);
    hipLaunchKernelGGL(attn_out2, dim3(49*8), dim3(512), 0, stream,
                       qkt_hi, qkt_lo, vbf, mrowp, lrowp, x, gm, out);
}

// Round 4
// 559.277 us; speedup vs baseline: 5.9837x; 1.2426x over previous
//
#include <hip/hip_runtime.h>
#include <math.h>

// Problem constants
#define B_ 8
#define C_ 256
#define H_ 56
#define W_ 56
#define N_ 3136  // 56*56 = 49*64

typedef __attribute__((ext_vector_type(8))) short short8;
typedef __attribute__((ext_vector_type(4))) short short4v;
typedef __attribute__((ext_vector_type(4))) float f32x4;
typedef __attribute__((ext_vector_type(16))) float f32x16;
typedef __attribute__((ext_vector_type(4))) unsigned short u16x4;
#define MFMA16(A, Bf, Cf) __builtin_amdgcn_mfma_f32_16x16x32_bf16((A), (Bf), (Cf), 0, 0, 0)
#define MFMA32(A, Bf, Cf) __builtin_amdgcn_mfma_f32_32x32x16_bf16((A), (Bf), (Cf), 0, 0, 0)

// -------------------- workspace layout (ushort units) --------------------
#define XT_ELEMS (B_*58*64*256)           // 7,602,176
#define A_ELEMS  (320*2304)               // 737,280
#define AHI_OFF  (2*XT_ELEMS)
#define ALO_OFF  (AHI_OFF + A_ELEMS)
#define QKT_HI_OFF (ALO_OFF + A_ELEMS)
#define QKT_ELEMS  (B_*N_*64)             // 1,605,632
#define QKT_LO_OFF (QKT_HI_OFF + QKT_ELEMS)
#define VBF_OFF    (QKT_LO_OFF + QKT_ELEMS)
#define VBF_ELEMS  (B_*C_*N_)             // 6,422,528
#define F32_BYTE_OFF ((size_t)(VBF_OFF + VBF_ELEMS) * 2)
#define M_OFF 0
#define L_OFF (B_*N_)

// LDS swizzle for conv B-slabs: chunk (r,col,c8) -> uint4 index
#define SWZ(r, col, c8) ((((r)*64 + (col))*4) + ((c8) ^ ((col) & 3)))

__device__ inline unsigned short f2bf(float f) {
    unsigned u = __float_as_uint(f);
    unsigned r = (u + 0x7fffu + ((u >> 16) & 1u)) >> 16;   // RNE
    return (unsigned short)r;
}
__device__ inline float bf2f(unsigned short h) {
    return __uint_as_float(((unsigned)h) << 16);
}

// ---------------------------------------------------------------------------
// Kernel 0: zero the padded x regions.
// ---------------------------------------------------------------------------
__global__ __launch_bounds__(256) void zero_pads(uint4* __restrict__ p, int n16)
{
    const int stride = gridDim.x * 256;
    for (int i = blockIdx.x * 256 + threadIdx.x; i < n16; i += stride)
        p[i] = make_uint4(0, 0, 0, 0);
}

// ---------------------------------------------------------------------------
// Kernel 1a: x (fp32 NCHW) -> padded pixel-major bf16 hi/lo.
// ---------------------------------------------------------------------------
__global__ __launch_bounds__(256) void prep_x(
    const float* __restrict__ x,
    unsigned short* __restrict__ xhi, unsigned short* __restrict__ xlo)
{
    __shared__ float xs[64][57];
    const int cc = blockIdx.x, y = blockIdx.y, b = blockIdx.z;
    const int t = threadIdx.x;
    const int c0 = cc * 64;
    for (int idx = t; idx < 64 * 56; idx += 256) {
        const int ch = idx / 56, xc = idx - ch * 56;
        xs[ch][xc] = x[((size_t)(b*C_ + c0 + ch)*H_ + y)*W_ + xc];
    }
    __syncthreads();
    for (int idx = t; idx < 56 * 32; idx += 256) {
        const int xc = idx >> 5, chp = idx & 31;
        const float v0 = xs[2*chp][xc], v1 = xs[2*chp + 1][xc];
        const unsigned short h0 = f2bf(v0), h1 = f2bf(v1);
        const unsigned short l0 = f2bf(v0 - bf2f(h0));
        const unsigned short l1 = f2bf(v1 - bf2f(h1));
        const size_t o = ((size_t)(b*58 + y + 1) * 64 + (xc + 1)) * 256 + c0 + 2*chp;
        *(unsigned*)(xhi + o) = (unsigned)h0 | ((unsigned)h1 << 16);
        *(unsigned*)(xlo + o) = (unsigned)l0 | ((unsigned)l1 << 16);
    }
}

// ---------------------------------------------------------------------------
// Kernel 1b: weights -> A_hi/A_lo [320][2304], k = s*256 + c.
// ---------------------------------------------------------------------------
__global__ __launch_bounds__(256) void prep_w(
    const float* __restrict__ wq, const float* __restrict__ wk,
    const float* __restrict__ wv,
    unsigned short* __restrict__ Ahi, unsigned short* __restrict__ Alo)
{
    const int g = blockIdx.x * 256 + threadIdx.x;
    if (g >= 320 * 2304) return;
    const int m = g / 2304, k = g - m * 2304;
    const int s = k >> 8, c = k & 255;
    float w;
    if (m < 32)      w = wq[((size_t)m*C_ + c)*9 + s];
    else if (m < 64) w = wk[((size_t)(m-32)*C_ + c)*9 + s];
    else             w = wv[((size_t)(m-64)*C_ + c)*9 + s];
    const unsigned short h = f2bf(w);
    Ahi[g] = h;
    Alo[g] = f2bf(w - bf2f(h));
}

// ---------------------------------------------------------------------------
// Kernel 2a: q/k conv (bf16x3). grid (b 8, yt 28), block 256 = 4 waves.
// Block: m = 64 qk rows (hi+lo), n = 2 y-rows x 64 px. LDS: x slab rows
// y0-1..y0+2 (hi+lo, swizzled). Wave (wm,wn): m 32 x n 64.
// Register-prefetch next c-chunk while MFMAs run.
// ---------------------------------------------------------------------------
__global__ __launch_bounds__(256, 2) void conv_qk(
    const unsigned short* __restrict__ xhi, const unsigned short* __restrict__ xlo,
    const unsigned short* __restrict__ Ahi, const unsigned short* __restrict__ Alo,
    const float* __restrict__ bq, const float* __restrict__ bk,
    unsigned short* __restrict__ qkt_hi, unsigned short* __restrict__ qkt_lo)
{
    __shared__ uint4 sH[4*64*4];   // 16 KB
    __shared__ uint4 sL[4*64*4];   // 16 KB
    const int b = blockIdx.x, yt = blockIdx.y;
    const int y0 = yt * 2;
    const int t = threadIdx.x;
    const int w = t >> 6, L = t & 63;
    const int ln = L & 15, quad = L >> 4;
    const int wm = w & 1, wn = w >> 1;

    f32x4 acc[2][4];
#pragma unroll
    for (int mt = 0; mt < 2; mt++)
#pragma unroll
        for (int nt = 0; nt < 4; nt++) acc[mt][nt] = (f32x4)0.0f;

    uint4 ph[4], pl[4];
#pragma unroll
    for (int i = 0; i < 4; i++) {
        const int idx = t + i*256;
        const int r = idx >> 8, col = (idx >> 2) & 63, c8 = idx & 3;
        const size_t go = ((size_t)((b*58 + y0 + r)*64 + col))*256 + c8*8;
        ph[i] = *(const uint4*)(xhi + go);
        pl[i] = *(const uint4*)(xlo + go);
    }

    for (int cc = 0; cc < 8; cc++) {
        __syncthreads();
#pragma unroll
        for (int i = 0; i < 4; i++) {
            const int idx = t + i*256;
            const int r = idx >> 8, col = (idx >> 2) & 63, c8 = idx & 3;
            sH[SWZ(r, col, c8)] = ph[i];
            sL[SWZ(r, col, c8)] = pl[i];
        }
        __syncthreads();
        if (cc < 7) {
#pragma unroll
            for (int i = 0; i < 4; i++) {
                const int idx = t + i*256;
                const int r = idx >> 8, col = (idx >> 2) & 63, c8 = idx & 3;
                const size_t go = ((size_t)((b*58 + y0 + r)*64 + col))*256 + (cc+1)*32 + c8*8;
                ph[i] = *(const uint4*)(xhi + go);
                pl[i] = *(const uint4*)(xlo + go);
            }
        }
#pragma unroll
        for (int s = 0; s < 9; s++) {
            const int dy = s / 3 - 1, dx = s % 3 - 1;
            short8 ah[2], al[2];
#pragma unroll
            for (int mt = 0; mt < 2; mt++) {
                const size_t off = (size_t)(wm*32 + mt*16 + ln)*2304 + s*256 + cc*32 + quad*8;
                ah[mt] = *(const short8*)(Ahi + off);
                al[mt] = *(const short8*)(Alo + off);
            }
            const int r = wn + dy + 1;
            short8 bh[4], bl[4];
#pragma unroll
            for (int nt = 0; nt < 4; nt++) {
                const int col = nt*16 + ln + dx + 1;
                const int i4 = SWZ(r, col, quad);
                bh[nt] = *(const short8*)&sH[i4];
                bl[nt] = *(const short8*)&sL[i4];
            }
#pragma unroll
            for (int mt = 0; mt < 2; mt++)
#pragma unroll
                for (int nt = 0; nt < 4; nt++) {
                    acc[mt][nt] = MFMA16(ah[mt], bh[nt], acc[mt][nt]);
                    acc[mt][nt] = MFMA16(ah[mt], bl[nt], acc[mt][nt]);
                    acc[mt][nt] = MFMA16(al[mt], bh[nt], acc[mt][nt]);
                }
        }
    }

    // epilogue: C/D col = ln (px), row = quad*4 + r (m)
    const int y = y0 + wn;
#pragma unroll
    for (int nt = 0; nt < 4; nt++) {
        const int px = nt*16 + ln;
        if (px >= 56) continue;
        const int pix = y*56 + px;
#pragma unroll
        for (int mt = 0; mt < 2; mt++) {
            u16x4 hi4, lo4;
#pragma unroll
            for (int r = 0; r < 4; r++) {
                const int m = wm*32 + mt*16 + quad*4 + r;
                const float bias = (m < 32) ? bq[m] : bk[m - 32];
                const float val = acc[mt][nt][r] + bias;
                const unsigned short h = f2bf(val);
                hi4[r] = h;
                lo4[r] = f2bf(val - bf2f(h));
            }
            const size_t o = (size_t)(b*N_ + pix)*64 + wm*32 + mt*16 + quad*4;
            *(u16x4*)(qkt_hi + o) = hi4;
            *(u16x4*)(qkt_lo + o) = lo4;
        }
    }
}

// ---------------------------------------------------------------------------
// Kernel 2b: v conv (plain bf16). grid (b 8, yt 14, mg 2), block 512 = 8 waves.
// Block: m = 128 v rows, n = 4 y-rows x 64 px. LDS: x slab rows y0-1..y0+4
// (hi only). Wave (wm,wn): m 64 x n 64.
// ---------------------------------------------------------------------------
__global__ __launch_bounds__(512, 2) void conv_v(
    const unsigned short* __restrict__ xhi,
    const unsigned short* __restrict__ Ahi,
    const float* __restrict__ bv,
    unsigned short* __restrict__ vbf)
{
    __shared__ uint4 sH[6*64*4];   // 24 KB
    const int b = blockIdx.x, yt = blockIdx.y, mg = blockIdx.z;
    const int y0 = yt * 4;
    const int t = threadIdx.x;
    const int w = t >> 6, L = t & 63;
    const int ln = L & 15, quad = L >> 4;
    const int wm = w & 1, wn = w >> 1;
    const int m0 = 64 + mg*128 + wm*64;   // A row base

    f32x4 acc[4][4];
#pragma unroll
    for (int mt = 0; mt < 4; mt++)
#pragma unroll
        for (int nt = 0; nt < 4; nt++) acc[mt][nt] = (f32x4)0.0f;

    uint4 ph[3];
#pragma unroll
    for (int i = 0; i < 3; i++) {
        const int idx = t + i*512;
        const int r = idx >> 8, col = (idx >> 2) & 63, c8 = idx & 3;
        const size_t go = ((size_t)((b*58 + y0 + r)*64 + col))*256 + c8*8;
        ph[i] = *(const uint4*)(xhi + go);
    }

    for (int cc = 0; cc < 8; cc++) {
        __syncthreads();
#pragma unroll
        for (int i = 0; i < 3; i++) {
            const int idx = t + i*512;
            const int r = idx >> 8, col = (idx >> 2) & 63, c8 = idx & 3;
            sH[SWZ(r, col, c8)] = ph[i];
        }
        __syncthreads();
        if (cc < 7) {
#pragma unroll
            for (int i = 0; i < 3; i++) {
                const int idx = t + i*512;
                const int r = idx >> 8, col = (idx >> 2) & 63, c8 = idx & 3;
                const size_t go = ((size_t)((b*58 + y0 + r)*64 + col))*256 + (cc+1)*32 + c8*8;
                ph[i] = *(const uint4*)(xhi + go);
            }
        }
#pragma unroll
        for (int s = 0; s < 9; s++) {
            const int dy = s / 3 - 1, dx = s % 3 - 1;
            short8 a[4];
#pragma unroll
            for (int mt = 0; mt < 4; mt++) {
                const size_t off = (size_t)(m0 + mt*16 + ln)*2304 + s*256 + cc*32 + quad*8;
                a[mt] = *(const short8*)(Ahi + off);
            }
            const int r = wn + dy + 1;
            short8 bf[4];
#pragma unroll
            for (int nt = 0; nt < 4; nt++) {
                const int col = nt*16 + ln + dx + 1;
                bf[nt] = *(const short8*)&sH[SWZ(r, col, quad)];
            }
#pragma unroll
            for (int mt = 0; mt < 4; mt++)
#pragma unroll
                for (int nt = 0; nt < 4; nt++)
                    acc[mt][nt] = MFMA16(a[mt], bf[nt], acc[mt][nt]);
        }
    }

    // epilogue: v channel c = m - 64
    const int y = y0 + wn;
#pragma unroll
    for (int nt = 0; nt < 4; nt++) {
        const int px = nt*16 + ln;
        if (px >= 56) continue;
        const int pix = y*56 + px;
#pragma unroll
        for (int mt = 0; mt < 4; mt++) {
#pragma unroll
            for (int r = 0; r < 4; r++) {
                const int c = mg*128 + wm*64 + mt*16 + quad*4 + r;
                vbf[(size_t)(b*C_ + c)*N_ + pix] = f2bf(acc[mt][nt][r] + bv[c]);
            }
        }
    }
}

// ---------------------------------------------------------------------------
// Kernel 3: softmax statistics via MFMA (bf16x3 S). grid 392 (b = id&7),
// block 256 = 4 waves; wave w owns i-rows [it*64+w*16, +16), all j.
// ---------------------------------------------------------------------------
__global__ __launch_bounds__(256) void attn_ml2(
    const unsigned short* __restrict__ qkt_hi, const unsigned short* __restrict__ qkt_lo,
    float* __restrict__ mrow, float* __restrict__ lrow)
{
    const int bid = blockIdx.x;
    const int b = bid & 7, it = bid >> 3;
    const int t = threadIdx.x;
    const int w = t >> 6, L = t & 63;
    const int ln = L & 15, quad = L >> 4;

    const size_t qoff = (size_t)(b*N_ + it*64 + w*16 + ln)*64 + quad*8;
    const short8 qh = *(const short8*)(qkt_hi + qoff);
    const short8 ql = *(const short8*)(qkt_lo + qoff);

    float m_run[4], l_run[4];
#pragma unroll
    for (int r = 0; r < 4; r++) { m_run[r] = -INFINITY; l_run[r] = 0.0f; }

    for (int jt = 0; jt < 49; jt++) {
        f32x4 sacc[4];
#pragma unroll
        for (int tj = 0; tj < 4; tj++) {
            const size_t koff = (size_t)(b*N_ + jt*64 + tj*16 + ln)*64 + 32 + quad*8;
            const short8 kh = *(const short8*)(qkt_hi + koff);
            const short8 kl = *(const short8*)(qkt_lo + koff);
            f32x4 a = (f32x4)0.0f;
            a = MFMA16(qh, kh, a);
            a = MFMA16(qh, kl, a);
            a = MFMA16(ql, kh, a);
            sacc[tj] = a;
        }
#pragma unroll
        for (int r = 0; r < 4; r++) {
            float tm = fmaxf(fmaxf(sacc[0][r], sacc[1][r]), fmaxf(sacc[2][r], sacc[3][r]));
            tm = fmaxf(tm, __shfl_xor(tm, 1));
            tm = fmaxf(tm, __shfl_xor(tm, 2));
            tm = fmaxf(tm, __shfl_xor(tm, 4));
            tm = fmaxf(tm, __shfl_xor(tm, 8));
            const float m_new = fmaxf(m_run[r], tm);
            float ps = __expf(sacc[0][r] - m_new) + __expf(sacc[1][r] - m_new)
                     + __expf(sacc[2][r] - m_new) + __expf(sacc[3][r] - m_new);
            ps += __shfl_xor(ps, 1);
            ps += __shfl_xor(ps, 2);
            ps += __shfl_xor(ps, 4);
            ps += __shfl_xor(ps, 8);
            l_run[r] = l_run[r] * __expf(m_run[r] - m_new) + ps;
            m_run[r] = m_new;
        }
    }
    if (ln == 0) {
#pragma unroll
        for (int r = 0; r < 4; r++) {
            const int row = it*64 + w*16 + quad*4 + r;
            mrow[(size_t)b*N_ + row] = m_run[r];
            lrow[(size_t)b*N_ + row] = 1.0f / l_run[r];
        }
    }
}

// ---------------------------------------------------------------------------
// Kernel 4: output pass. Recompute S, P=exp(S-m)*rl -> bf16 LDS, PV via
// mfma 32x32x16. grid 392, block 512.
// ---------------------------------------------------------------------------
__global__ __launch_bounds__(512) void attn_out2(
    const unsigned short* __restrict__ qkt_hi, const unsigned short* __restrict__ qkt_lo,
    const unsigned short* __restrict__ vbf,
    const float* __restrict__ mrow, const float* __restrict__ lrow,
    const float* __restrict__ x, const float* __restrict__ gptr,
    float* __restrict__ out)
{
    __shared__ unsigned short P[64*68];
    const int bid = blockIdx.x;
    const int b = bid & 7, it = bid >> 3;
    const int t = threadIdx.x;
    const int w = t >> 6, L = t & 63;
    const int ln = L & 15, quad = L >> 4;
    const int ti = w & 3, tjb = (w >> 2) * 2;
    const int l32 = L & 31, h32 = L >> 5;

    const size_t qoff = (size_t)(b*N_ + it*64 + ti*16 + ln)*64 + quad*8;
    const short8 qh = *(const short8*)(qkt_hi + qoff);
    const short8 ql = *(const short8*)(qkt_lo + qoff);

    float mr[4], rl[4];
#pragma unroll
    for (int r = 0; r < 4; r++) {
        const int row = it*64 + ti*16 + quad*4 + r;
        mr[r] = mrow[(size_t)b*N_ + row];
        rl[r] = lrow[(size_t)b*N_ + row];
    }

    f32x16 O0 = (f32x16)0.0f, O1 = (f32x16)0.0f;
    const unsigned short* vrow = vbf + (size_t)(b*C_ + w*32 + l32) * N_;

    for (int jt = 0; jt < 49; jt++) {
        f32x4 sacc[2];
#pragma unroll
        for (int u = 0; u < 2; u++) {
            const int tj = tjb + u;
            const size_t koff = (size_t)(b*N_ + jt*64 + tj*16 + ln)*64 + 32 + quad*8;
            const short8 kh = *(const short8*)(qkt_hi + koff);
            const short8 kl = *(const short8*)(qkt_lo + koff);
            f32x4 a = (f32x4)0.0f;
            a = MFMA16(qh, kh, a);
            a = MFMA16(qh, kl, a);
            a = MFMA16(ql, kh, a);
            sacc[u] = a;
        }
        if (jt) __syncthreads();
#pragma unroll
        for (int u = 0; u < 2; u++) {
            const int tj = tjb + u;
#pragma unroll
            for (int r = 0; r < 4; r++) {
                const float p = __expf(sacc[u][r] - mr[r]) * rl[r];
                P[(ti*16 + quad*4 + r)*68 + tj*16 + ln] = f2bf(p);
            }
        }
        __syncthreads();

        const unsigned short* vj = vrow + jt*64;
#pragma unroll
        for (int s = 0; s < 4; s++) {
            const short8 Af = *(const short8*)(vj + s*16 + h32*8);
            short8 B0, B1;
            {
                const unsigned short* p0 = &P[(l32)*68 + s*16 + h32*8];
                *(short4v*)&B0       = *(const short4v*)(p0);
                *((short4v*)&B0 + 1) = *(const short4v*)(p0 + 4);
                const unsigned short* p1 = &P[(32 + l32)*68 + s*16 + h32*8];
                *(short4v*)&B1       = *(const short4v*)(p1);
                *((short4v*)&B1 + 1) = *(const short4v*)(p1 + 4);
            }
            O0 = MFMA32(Af, B0, O0);
            O1 = MFMA32(Af, B1, O1);
        }
    }

    const float gamma = gptr[0];
#pragma unroll
    for (int itile = 0; itile < 2; itile++) {
        const f32x16 Ot = itile ? O1 : O0;
        const int pix = it*64 + itile*32 + l32;
#pragma unroll
        for (int reg = 0; reg < 16; reg++) {
            const int c = w*32 + (reg & 3) + 8*(reg >> 2) + 4*h32;
            const size_t idx = (size_t)(b*C_ + c)*N_ + pix;
            out[idx] = fmaf(gamma, Ot[reg], x[idx]);
        }
    }
}

// ---------------------------------------------------------------------------
extern "C" void kernel_launch(void* const* d_in, const int* in_sizes, int n_in,
                              void* d_out, int out_size, void* d_ws, size_t ws_size,
                              hipStream_t stream)
{
    (void)in_sizes; (void)n_in; (void)out_size; (void)ws_size;
    const float* x  = (const float*)d_in[0];
    const float* wq = (const float*)d_in[1];
    const float* bq = (const float*)d_in[2];
    const float* wk = (const float*)d_in[3];
    const float* bk = (const float*)d_in[4];
    const float* wv = (const float*)d_in[5];
    const float* bv = (const float*)d_in[6];
    const float* gm = (const float*)d_in[7];
    float* out = (float*)d_out;

    unsigned short* u = (unsigned short*)d_ws;
    unsigned short* xhi = u;
    unsigned short* xlo = u + XT_ELEMS;
    unsigned short* Ahi = u + AHI_OFF;
    unsigned short* Alo = u + ALO_OFF;
    unsigned short* qkt_hi = u + QKT_HI_OFF;
    unsigned short* qkt_lo = u + QKT_LO_OFF;
    unsigned short* vbf = u + VBF_OFF;
    float* f32 = (float*)((char*)d_ws + F32_BYTE_OFF);
    float* mrowp = f32 + M_OFF;
    float* lrowp = f32 + L_OFF;

    hipLaunchKernelGGL(zero_pads, dim3(1024), dim3(256), 0, stream,
                       (uint4*)d_ws, (2*XT_ELEMS*2)/16);
    hipLaunchKernelGGL(prep_x, dim3(4, 56, 8), dim3(256), 0, stream, x, xhi, xlo);
    hipLaunchKernelGGL(prep_w, dim3(2880), dim3(256), 0, stream, wq, wk, wv, Ahi, Alo);
    hipLaunchKernelGGL(conv_qk, dim3(8, 28), dim3(256), 0, stream,
                       xhi, xlo, Ahi, Alo, bq, bk, qkt_hi, qkt_lo);
    hipLaunchKernelGGL(conv_v, dim3(8, 14, 2), dim3(512), 0, stream,
                       xhi, Ahi, bv, vbf);
    hipLaunchKernelGGL(attn_ml2, dim3(49*8), dim3(256), 0, stream,
                       qkt_hi, qkt_lo, mrowp, lrowp);
    hipLaunchKernelGGL(attn_out2, dim3(49*8), dim3(512), 0, stream,
                       qkt_hi, qkt_lo, vbf, mrowp, lrowp, x, gm, out);
}